// Round 7
// baseline (328.247 us; speedup 1.0000x reference)
//
#include <hip/hip_runtime.h>
#include <hip/hip_bf16.h>
#include <math.h>

#define Bn 64
#define Tn 256
#define Cn 384
#define Hn 6
#define HSn 64
#define FFn 1536
#define EPSn 1e-3f
#define SECn 6291456  // B*H*T*HS = one q/k/v section, elements

typedef __attribute__((ext_vector_type(4))) float f32x4;
typedef __attribute__((ext_vector_type(8))) short short8;

__device__ __forceinline__ void async_copy16(void* lds, const void* g) {
    __builtin_amdgcn_global_load_lds(
        (const __attribute__((address_space(1))) void*)g,
        (__attribute__((address_space(3))) void*)lds, 16, 0, 0);
}

// ---------------- LayerNorm -> bf16 (one block per row, 128 threads) ----------------
__global__ __launch_bounds__(128) void ln_bf16_kernel(const float* __restrict__ x,
                                                      const float* __restrict__ g,
                                                      const float* __restrict__ be,
                                                      __hip_bfloat16* __restrict__ out) {
    int row = blockIdx.x;
    int tid = threadIdx.x;
    const float* xr = x + (size_t)row * Cn;
    float v0 = xr[tid], v1 = xr[tid + 128], v2 = xr[tid + 256];
    float s = v0 + v1 + v2;
    __shared__ float red[4];
#pragma unroll
    for (int off = 32; off; off >>= 1) s += __shfl_xor(s, off);
    if ((tid & 63) == 0) red[tid >> 6] = s;
    __syncthreads();
    float mu = (red[0] + red[1]) * (1.0f / Cn);
    float d0 = v0 - mu, d1 = v1 - mu, d2 = v2 - mu;
    float sq = d0 * d0 + d1 * d1 + d2 * d2;
#pragma unroll
    for (int off = 32; off; off >>= 1) sq += __shfl_xor(sq, off);
    if ((tid & 63) == 0) red[2 + (tid >> 6)] = sq;
    __syncthreads();
    float var = (red[2] + red[3]) * (1.0f / Cn);
    float r = rsqrtf(var + EPSn);
    __hip_bfloat16* orow = out + (size_t)row * Cn;
    orow[tid]       = __float2bfloat16(d0 * r * g[tid]       + be[tid]);
    orow[tid + 128] = __float2bfloat16(d1 * r * g[tid + 128] + be[tid + 128]);
    orow[tid + 256] = __float2bfloat16(d2 * r * g[tid + 256] + be[tid + 256]);
}

// ---------------- Pack a [K,N] row-major fp32 weight into MFMA B-fragment order ----------------
__global__ __launch_bounds__(256) void pack_b_kernel(const float* __restrict__ W,
                                                     __hip_bfloat16* __restrict__ out,
                                                     int K, int N) {
    int id = blockIdx.x * 256 + threadIdx.x;
    if (id >= K * N) return;
    int tile = id >> 9, lane = (id >> 3) & 63, j = id & 7;
    int ntiles = N >> 4;
    int k = (tile / ntiles) * 32 + ((lane >> 4) << 3) + j;
    int n = (tile % ntiles) * 16 + (lane & 15);
    out[id] = __float2bfloat16(W[(size_t)k * N + n]);
}

// ---------------- Pack fused [Wq|Wk|Wv] into one B [K=384, N=1152] ----------------
__global__ __launch_bounds__(256) void pack_qkv_kernel(const float* __restrict__ Wq,
                                                       const float* __restrict__ Wk,
                                                       const float* __restrict__ Wv,
                                                       __hip_bfloat16* __restrict__ out) {
    int id = blockIdx.x * 256 + threadIdx.x;
    if (id >= Cn * 1152) return;
    int tile = id >> 9, lane = (id >> 3) & 63, j = id & 7;
    int k = (tile / 72) * 32 + ((lane >> 4) << 3) + j;
    int n = (tile % 72) * 16 + (lane & 15);
    int sec = n / Cn, rem = n % Cn;
    int hh = rem >> 6, d = rem & 63;
    const float* W = (sec == 0) ? Wq : ((sec == 1) ? Wk : Wv);
    out[id] = __float2bfloat16(W[((size_t)hh * Cn + k) * HSn + d]);
}

// ---------------- MFMA GEMM, m97-style LDS-staged: C[M,NN] = A @ Bpacked ----------------
template <int KK, int NN, int EPI>
__global__ __launch_bounds__(256) void gemm_mfma(const __hip_bfloat16* __restrict__ A,
                                                 const __hip_bfloat16* __restrict__ Bp,
                                                 const float* __restrict__ bias,
                                                 const float* __restrict__ resid,
                                                 float* __restrict__ outF,
                                                 __hip_bfloat16* __restrict__ outB) {
    constexpr int GX = NN / 64;
    __shared__ short Atile[8 * 512];  // 8 KB
    __shared__ short Btile[4 * 512];  // 4 KB

    int l = blockIdx.x;
    int xcd = l & 7, i = l >> 3;
    int rowblk = xcd * 16 + i / GX;
    int colblk = i - (i / GX) * GX;

    int lane = threadIdx.x & 63, wave = threadIdx.x >> 6;
    int lrow = lane & 15, lquad = lane >> 4;
    int m0 = rowblk * 128;
    int n0 = colblk * 64;

    f32x4 acc[2][4];
#pragma unroll
    for (int st = 0; st < 2; st++)
#pragma unroll
        for (int nt = 0; nt < 4; nt++) acc[st][nt] = (f32x4){0.f, 0.f, 0.f, 0.f};

    const short* As = (const short*)A;
    const short* Bs = (const short*)Bp;

    for (int kb = 0; kb < KK; kb += 32) {
        __syncthreads();
#pragma unroll
        for (int p = 0; p < 2; p++) {
            int s = p * 4 + wave;
            const short* ga = As + (size_t)(m0 + s * 16 + lrow) * KK + kb + lquad * 8;
            async_copy16(&Atile[s * 512], ga);
        }
        {
            int tb0 = (kb >> 5) * (NN >> 4) + (n0 >> 4);
            const short* gb = Bs + (size_t)(tb0 + wave) * 512 + lane * 8;
            async_copy16(&Btile[wave * 512], gb);
        }
        __syncthreads();
        short8 af0 = *(const short8*)(&Atile[(2 * wave) * 512 + lane * 8]);
        short8 af1 = *(const short8*)(&Atile[(2 * wave + 1) * 512 + lane * 8]);
#pragma unroll
        for (int nt = 0; nt < 4; nt++) {
            short8 bf = *(const short8*)(&Btile[nt * 512 + lane * 8]);
            acc[0][nt] = __builtin_amdgcn_mfma_f32_16x16x32_bf16(af0, bf, acc[0][nt], 0, 0, 0);
            acc[1][nt] = __builtin_amdgcn_mfma_f32_16x16x32_bf16(af1, bf, acc[1][nt], 0, 0, 0);
        }
    }

#pragma unroll
    for (int st = 0; st < 2; st++) {
        int mbase = m0 + (2 * wave + st) * 16;
#pragma unroll
        for (int nt = 0; nt < 4; nt++) {
            int n = n0 + nt * 16 + lrow;
#pragma unroll
            for (int r = 0; r < 4; r++) {
                int m = mbase + lquad * 4 + r;
                float vv = acc[st][nt][r];
                if (EPI == 0) {
                    int b = m >> 8, t = m & 255;
                    int sec = n / Cn, rem = n % Cn;
                    int hh = rem >> 6, d = rem & 63;
                    if (sec < 2) {
                        outB[(size_t)sec * SECn + ((((size_t)b * Hn + hh) << 8) + t) * HSn + d] =
                            __float2bfloat16(vv);
                    } else {
                        int bh2 = b * Hn + hh;
                        int tile = ((t >> 5) << 2) + (d >> 4);
                        int lanev = (((t >> 3) & 3) << 4) + (d & 15);
                        outB[(size_t)2 * SECn + (size_t)bh2 * 16384 + tile * 512 + lanev * 8 +
                             (t & 7)] = __float2bfloat16(vv);
                    }
                } else if (EPI == 1) {
                    size_t idx = (size_t)m * NN + n;
                    outF[idx] = resid[idx] + vv + bias[n];
                } else {
                    float y = vv + bias[n];
                    outB[(size_t)m * NN + n] = __float2bfloat16(fmaxf(y, 0.0f));
                }
            }
        }
    }
}

// ---------------- Flash-style MFMA attention: ONE WAVE per block ----------------
// grid (16, B*H), 64 threads. Block handles Q-tile qt = 15 - blockIdx.x (heavy first).
// V read fragment-direct from global (pre-packed by QKV epilogue); P transforms
// C-layout -> A-layout through an 8 KB per-block LDS region. No barriers.
__global__ __launch_bounds__(64) void attn_mfma_kernel(const __hip_bfloat16* __restrict__ q,
                                                       const __hip_bfloat16* __restrict__ k,
                                                       const __hip_bfloat16* __restrict__ vp,
                                                       __hip_bfloat16* __restrict__ o) {
    __shared__ short Pw[4096];  // 8 KB: P in A-fragment packed layout (8 x 32-wide tiles)
    int qt = 15 - (int)blockIdx.x;  // heavy tiles dispatch first -> tail packs
    int bh = blockIdx.y;
    int b = bh / Hn, hh = bh - b * Hn;
    int lane = threadIdx.x;
    int c16 = lane & 15, quad = lane >> 4;

    const short* qs = (const short*)q + (size_t)bh * Tn * HSn;
    const short* ks = (const short*)k + (size_t)bh * Tn * HSn;
    const short* vs = (const short*)vp + (size_t)bh * 16384;  // packed B-frag tiles

    int qrow0 = qt * 16;
    int st_max = qt;                   // highest 16-wide score tile with any valid col
    int kb_count = (st_max + 2) >> 1;  // 32-wide k-blocks for PV
    int covered = kb_count * 2;        // P tiles PV reads (zero-fill beyond st_max)

    const short* qrow = qs + (qrow0 + c16) * HSn + quad * 8;
    short8 aq0 = *(const short8*)(qrow);
    short8 aq1 = *(const short8*)(qrow + 32);

    // prefetch V k-block 0 fragments (always needed) to overlap softmax VALU
    short8 bv0[4];
#pragma unroll
    for (int nt = 0; nt < 4; nt++) bv0[nt] = *(const short8*)(vs + nt * 512 + lane * 8);

    f32x4 accS[16];
#pragma unroll
    for (int st = 0; st < 16; st++) accS[st] = (f32x4){0.f, 0.f, 0.f, 0.f};
#pragma unroll
    for (int st = 0; st < 16; st++) {
        if (st <= st_max) {
            const short* kr = ks + (st * 16 + c16) * HSn + quad * 8;
            short8 bk0 = *(const short8*)(kr);
            short8 bk1 = *(const short8*)(kr + 32);
            accS[st] = __builtin_amdgcn_mfma_f32_16x16x32_bf16(aq0, bk0, accS[st], 0, 0, 0);
            accS[st] = __builtin_amdgcn_mfma_f32_16x16x32_bf16(aq1, bk1, accS[st], 0, 0, 0);
        }
    }

    float inv[4];
#pragma unroll
    for (int r = 0; r < 4; r++) {
        int row = qrow0 + quad * 4 + r;
        float mx = -INFINITY;
#pragma unroll
        for (int st = 0; st < 16; st++) {
            if (st <= st_max) {
                int col = st * 16 + c16;
                float a = (col <= row) ? accS[st][r] * 0.125f : -INFINITY;
                accS[st][r] = a;
                mx = fmaxf(mx, a);
            }
        }
#pragma unroll
        for (int off = 8; off; off >>= 1) mx = fmaxf(mx, __shfl_xor(mx, off));
        float sum = 0.f;
#pragma unroll
        for (int st = 0; st < 16; st++) {
            if (st < covered) {
                float e = 0.0f;
                if (st <= st_max) {
                    e = __expf(accS[st][r] - mx);
                    sum += e;
                }
                int c = st * 16 + c16;
                __hip_bfloat16 pb = __float2bfloat16(e);
                Pw[(c >> 5) * 512 + (((c >> 3) & 3) * 16 + quad * 4 + r) * 8 + (c & 7)] =
                    *(short*)&pb;
            }
        }
#pragma unroll
        for (int off = 8; off; off >>= 1) sum += __shfl_xor(sum, off);
        inv[r] = 1.0f / sum;
    }

    f32x4 accO[4];
#pragma unroll
    for (int nt = 0; nt < 4; nt++) accO[nt] = (f32x4){0.f, 0.f, 0.f, 0.f};
    {
        short8 ap = *(const short8*)(Pw + lane * 8);
#pragma unroll
        for (int nt = 0; nt < 4; nt++)
            accO[nt] = __builtin_amdgcn_mfma_f32_16x16x32_bf16(ap, bv0[nt], accO[nt], 0, 0, 0);
    }
#pragma unroll
    for (int kbi = 1; kbi < 8; kbi++) {
        if (kbi < kb_count) {
            short8 ap = *(const short8*)(Pw + kbi * 512 + lane * 8);
#pragma unroll
            for (int nt = 0; nt < 4; nt++) {
                short8 bv = *(const short8*)(vs + (kbi * 4 + nt) * 512 + lane * 8);
                accO[nt] = __builtin_amdgcn_mfma_f32_16x16x32_bf16(ap, bv, accO[nt], 0, 0, 0);
            }
        }
    }

#pragma unroll
    for (int nt = 0; nt < 4; nt++) {
#pragma unroll
        for (int r = 0; r < 4; r++) {
            int t = qrow0 + quad * 4 + r;
            int d = nt * 16 + c16;
            o[(((size_t)b * Tn + t) * Hn + hh) * HSn + d] = __float2bfloat16(accO[nt][r] * inv[r]);
        }
    }
}

extern "C" void kernel_launch(void* const* d_in, const int* in_sizes, int n_in,
                              void* d_out, int out_size, void* d_ws, size_t ws_size,
                              hipStream_t stream) {
    const float* x  = (const float*)d_in[0];
    const float* Wq = (const float*)d_in[1];
    const float* Wk = (const float*)d_in[2];
    const float* Wv = (const float*)d_in[3];
    const float* Wp = (const float*)d_in[4];
    const float* bp = (const float*)d_in[5];
    const float* W1 = (const float*)d_in[6];
    const float* b1 = (const float*)d_in[7];
    const float* W2 = (const float*)d_in[8];
    const float* b2 = (const float*)d_in[9];
    const float* g1 = (const float*)d_in[10];
    const float* be1 = (const float*)d_in[11];
    const float* g2 = (const float*)d_in[12];
    const float* be2 = (const float*)d_in[13];

    const size_t M = (size_t)Bn * Tn;  // 16384
    __hip_bfloat16* ws  = (__hip_bfloat16*)d_ws;
    __hip_bfloat16* h   = ws;               // M*384 bf16 (LN1 out; reused as h2)
    __hip_bfloat16* big = h + M * Cn;       // M*1536 bf16: qkv (3*SECn; v packed) then y1
    __hip_bfloat16* o   = big + M * FFn;    // M*384 bf16 attention output [b,t,h,d]
    __hip_bfloat16* pQKV = o + M * Cn;      // 384*1152
    __hip_bfloat16* pWp  = pQKV + Cn * 1152;
    __hip_bfloat16* pW1  = pWp + Cn * Cn;
    __hip_bfloat16* pW2  = pW1 + Cn * FFn;

    float* x2 = (float*)d_out;

    pack_qkv_kernel<<<(Cn * 1152 + 255) / 256, 256, 0, stream>>>(Wq, Wk, Wv, pQKV);
    pack_b_kernel<<<(Cn * Cn + 255) / 256, 256, 0, stream>>>(Wp, pWp, Cn, Cn);
    pack_b_kernel<<<(Cn * FFn + 255) / 256, 256, 0, stream>>>(W1, pW1, Cn, FFn);
    pack_b_kernel<<<(FFn * Cn + 255) / 256, 256, 0, stream>>>(W2, pW2, FFn, Cn);

    // 1) h = LN1(x)
    ln_bf16_kernel<<<M, 128, 0, stream>>>(x, g1, be1, h);
    // 2) qkv  (GX=18 -> grid 2304); v section written fragment-packed
    gemm_mfma<Cn, 1152, 0><<<2304, 256, 0, stream>>>(h, pQKV, nullptr, nullptr, nullptr, big);
    // 3) attention: 6144 single-wave blocks
    attn_mfma_kernel<<<dim3(16, Bn * Hn), 64, 0, stream>>>(big, big + SECn, big + 2 * SECn, o);
    // 4) x2 = x + o@Wp + bp   (GX=6 -> 768)
    gemm_mfma<Cn, Cn, 1><<<768, 256, 0, stream>>>(o, pWp, bp, x, x2, nullptr);
    // 5) h2 = LN2(x2)
    ln_bf16_kernel<<<M, 128, 0, stream>>>(x2, g2, be2, h);
    // 6) y1 = relu(h2 @ W1 + b1)  (GX=24 -> 3072)
    gemm_mfma<Cn, FFn, 2><<<3072, 256, 0, stream>>>(h, pW1, b1, nullptr, nullptr, big);
    // 7) out = x2 + y1 @ W2 + b2  (GX=6 -> 768)
    gemm_mfma<FFn, Cn, 1><<<768, 256, 0, stream>>>(big, pW2, b2, x2, x2, nullptr);
}

// Round 8
// 304.761 us; speedup vs baseline: 1.0771x; 1.0771x over previous
//
#include <hip/hip_runtime.h>
#include <hip/hip_bf16.h>
#include <math.h>

#define Bn 64
#define Tn 256
#define Cn 384
#define Hn 6
#define HSn 64
#define FFn 1536
#define EPSn 1e-3f
#define SECn 6291456  // B*H*T*HS = one q/k/v section, elements

typedef __attribute__((ext_vector_type(4))) float f32x4;
typedef __attribute__((ext_vector_type(8))) short short8;

__device__ __forceinline__ void async_copy16(void* lds, const void* g) {
    __builtin_amdgcn_global_load_lds(
        (const __attribute__((address_space(1))) void*)g,
        (__attribute__((address_space(3))) void*)lds, 16, 0, 0);
}

// ---------------- LayerNorm -> bf16 (one block per row, 128 threads) ----------------
__global__ __launch_bounds__(128) void ln_bf16_kernel(const float* __restrict__ x,
                                                      const float* __restrict__ g,
                                                      const float* __restrict__ be,
                                                      __hip_bfloat16* __restrict__ out) {
    int row = blockIdx.x;
    int tid = threadIdx.x;
    const float* xr = x + (size_t)row * Cn;
    float v0 = xr[tid], v1 = xr[tid + 128], v2 = xr[tid + 256];
    float s = v0 + v1 + v2;
    __shared__ float red[4];
#pragma unroll
    for (int off = 32; off; off >>= 1) s += __shfl_xor(s, off);
    if ((tid & 63) == 0) red[tid >> 6] = s;
    __syncthreads();
    float mu = (red[0] + red[1]) * (1.0f / Cn);
    float d0 = v0 - mu, d1 = v1 - mu, d2 = v2 - mu;
    float sq = d0 * d0 + d1 * d1 + d2 * d2;
#pragma unroll
    for (int off = 32; off; off >>= 1) sq += __shfl_xor(sq, off);
    if ((tid & 63) == 0) red[2 + (tid >> 6)] = sq;
    __syncthreads();
    float var = (red[2] + red[3]) * (1.0f / Cn);
    float r = rsqrtf(var + EPSn);
    __hip_bfloat16* orow = out + (size_t)row * Cn;
    orow[tid]       = __float2bfloat16(d0 * r * g[tid]       + be[tid]);
    orow[tid + 128] = __float2bfloat16(d1 * r * g[tid + 128] + be[tid + 128]);
    orow[tid + 256] = __float2bfloat16(d2 * r * g[tid + 256] + be[tid + 256]);
}

// ---------------- Pack a [K,N] row-major fp32 weight into MFMA B-fragment order ----------------
__global__ __launch_bounds__(256) void pack_b_kernel(const float* __restrict__ W,
                                                     __hip_bfloat16* __restrict__ out,
                                                     int K, int N) {
    int id = blockIdx.x * 256 + threadIdx.x;
    if (id >= K * N) return;
    int tile = id >> 9, lane = (id >> 3) & 63, j = id & 7;
    int ntiles = N >> 4;
    int k = (tile / ntiles) * 32 + ((lane >> 4) << 3) + j;
    int n = (tile % ntiles) * 16 + (lane & 15);
    out[id] = __float2bfloat16(W[(size_t)k * N + n]);
}

// ---------------- Pack fused [Wq|Wk|Wv] into one B [K=384, N=1152] ----------------
__global__ __launch_bounds__(256) void pack_qkv_kernel(const float* __restrict__ Wq,
                                                       const float* __restrict__ Wk,
                                                       const float* __restrict__ Wv,
                                                       __hip_bfloat16* __restrict__ out) {
    int id = blockIdx.x * 256 + threadIdx.x;
    if (id >= Cn * 1152) return;
    int tile = id >> 9, lane = (id >> 3) & 63, j = id & 7;
    int k = (tile / 72) * 32 + ((lane >> 4) << 3) + j;
    int n = (tile % 72) * 16 + (lane & 15);
    int sec = n / Cn, rem = n % Cn;
    int hh = rem >> 6, d = rem & 63;
    const float* W = (sec == 0) ? Wq : ((sec == 1) ? Wk : Wv);
    out[id] = __float2bfloat16(W[((size_t)hh * Cn + k) * HSn + d]);
}

// ---------------- MFMA GEMM, m97-style LDS-staged: C[M,NN] = A @ Bpacked ----------------
template <int KK, int NN, int EPI>
__global__ __launch_bounds__(256) void gemm_mfma(const __hip_bfloat16* __restrict__ A,
                                                 const __hip_bfloat16* __restrict__ Bp,
                                                 const float* __restrict__ bias,
                                                 const float* __restrict__ resid,
                                                 float* __restrict__ outF,
                                                 __hip_bfloat16* __restrict__ outB) {
    constexpr int GX = NN / 64;
    __shared__ short Atile[8 * 512];  // 8 KB
    __shared__ short Btile[4 * 512];  // 4 KB

    int l = blockIdx.x;
    int xcd = l & 7, i = l >> 3;
    int rowblk = xcd * 16 + i / GX;
    int colblk = i - (i / GX) * GX;

    int lane = threadIdx.x & 63, wave = threadIdx.x >> 6;
    int lrow = lane & 15, lquad = lane >> 4;
    int m0 = rowblk * 128;
    int n0 = colblk * 64;

    f32x4 acc[2][4];
#pragma unroll
    for (int st = 0; st < 2; st++)
#pragma unroll
        for (int nt = 0; nt < 4; nt++) acc[st][nt] = (f32x4){0.f, 0.f, 0.f, 0.f};

    const short* As = (const short*)A;
    const short* Bs = (const short*)Bp;

    for (int kb = 0; kb < KK; kb += 32) {
        __syncthreads();
#pragma unroll
        for (int p = 0; p < 2; p++) {
            int s = p * 4 + wave;
            const short* ga = As + (size_t)(m0 + s * 16 + lrow) * KK + kb + lquad * 8;
            async_copy16(&Atile[s * 512], ga);
        }
        {
            int tb0 = (kb >> 5) * (NN >> 4) + (n0 >> 4);
            const short* gb = Bs + (size_t)(tb0 + wave) * 512 + lane * 8;
            async_copy16(&Btile[wave * 512], gb);
        }
        __syncthreads();
        short8 af0 = *(const short8*)(&Atile[(2 * wave) * 512 + lane * 8]);
        short8 af1 = *(const short8*)(&Atile[(2 * wave + 1) * 512 + lane * 8]);
#pragma unroll
        for (int nt = 0; nt < 4; nt++) {
            short8 bf = *(const short8*)(&Btile[nt * 512 + lane * 8]);
            acc[0][nt] = __builtin_amdgcn_mfma_f32_16x16x32_bf16(af0, bf, acc[0][nt], 0, 0, 0);
            acc[1][nt] = __builtin_amdgcn_mfma_f32_16x16x32_bf16(af1, bf, acc[1][nt], 0, 0, 0);
        }
    }

#pragma unroll
    for (int st = 0; st < 2; st++) {
        int mbase = m0 + (2 * wave + st) * 16;
#pragma unroll
        for (int nt = 0; nt < 4; nt++) {
            int n = n0 + nt * 16 + lrow;
#pragma unroll
            for (int r = 0; r < 4; r++) {
                int m = mbase + lquad * 4 + r;
                float vv = acc[st][nt][r];
                if (EPI == 0) {
                    int b = m >> 8, t = m & 255;
                    int sec = n / Cn, rem = n % Cn;
                    int hh = rem >> 6, d = rem & 63;
                    if (sec < 2) {
                        outB[(size_t)sec * SECn + ((((size_t)b * Hn + hh) << 8) + t) * HSn + d] =
                            __float2bfloat16(vv);
                    } else {
                        int bh2 = b * Hn + hh;
                        int tile = ((t >> 5) << 2) + (d >> 4);
                        int lanev = (((t >> 3) & 3) << 4) + (d & 15);
                        outB[(size_t)2 * SECn + (size_t)bh2 * 16384 + tile * 512 + lanev * 8 +
                             (t & 7)] = __float2bfloat16(vv);
                    }
                } else if (EPI == 1) {
                    size_t idx = (size_t)m * NN + n;
                    outF[idx] = resid[idx] + vv + bias[n];
                } else {
                    float y = vv + bias[n];
                    outB[(size_t)m * NN + n] = __float2bfloat16(fmaxf(y, 0.0f));
                }
            }
        }
    }
}

// ---------------- Flash-style MFMA attention: one block per (b,h), K in LDS ----------------
// 4 waves; wave w handles q-tiles {w, w+4, w+8, w+12}. K staged once to LDS in
// B-fragment layout (32 KB); V fragment-direct from global (L1-resident, 32 KB/bh);
// P per-wave 8 KB LDS region. One barrier total.
__global__ __launch_bounds__(256) void attn_mfma_kernel(const __hip_bfloat16* __restrict__ q,
                                                        const __hip_bfloat16* __restrict__ k,
                                                        const __hip_bfloat16* __restrict__ vp,
                                                        __hip_bfloat16* __restrict__ o) {
    __shared__ short Kl[16 * 1024];  // 32 KB: K tiles [st][chunk<2][512]
    __shared__ short Pl[4 * 4096];   // 32 KB: per-wave P in A-frag layout
    int bh = blockIdx.x;
    int b = bh / Hn, hh = bh - b * Hn;
    int tid = threadIdx.x;
    int lane = tid & 63, wave = tid >> 6;
    int c16 = lane & 15, quad = lane >> 4;

    const short* qs = (const short*)q + (size_t)bh * Tn * HSn;
    const short* ks = (const short*)k + (size_t)bh * Tn * HSn;
    const short* vs = (const short*)vp + (size_t)bh * 16384;  // packed B-frag tiles

    // ---- stage K once: tile st, chunk c -> Kl[st*1024 + c*512 + lane*8 + j] ----
#pragma unroll
    for (int i = 0; i < 4; i++) {
        int st = wave * 4 + i;
        const short* g0 = ks + (st * 16 + c16) * HSn + quad * 8;
        async_copy16(&Kl[st * 1024], g0);
        async_copy16(&Kl[st * 1024 + 512], g0 + 32);
    }
    __syncthreads();

    short* Pw = Pl + wave * 4096;

#pragma unroll
    for (int j = 0; j < 4; j++) {
        int qt = j * 4 + wave;
        int qrow0 = qt * 16;
        int st_max = qt;
        int kb_count = (st_max + 2) >> 1;
        int covered = kb_count * 2;

        const short* qrow = qs + (qrow0 + c16) * HSn + quad * 8;
        short8 aq0 = *(const short8*)(qrow);
        short8 aq1 = *(const short8*)(qrow + 32);

        f32x4 accS[16];
#pragma unroll
        for (int st = 0; st < 16; st++) accS[st] = (f32x4){0.f, 0.f, 0.f, 0.f};
#pragma unroll
        for (int st = 0; st < 16; st++) {
            if (st <= st_max) {
                short8 bk0 = *(const short8*)(&Kl[st * 1024 + lane * 8]);
                short8 bk1 = *(const short8*)(&Kl[st * 1024 + 512 + lane * 8]);
                accS[st] = __builtin_amdgcn_mfma_f32_16x16x32_bf16(aq0, bk0, accS[st], 0, 0, 0);
                accS[st] = __builtin_amdgcn_mfma_f32_16x16x32_bf16(aq1, bk1, accS[st], 0, 0, 0);
            }
        }

        float inv[4];
#pragma unroll
        for (int r = 0; r < 4; r++) {
            int row = qrow0 + quad * 4 + r;
            float mx = -INFINITY;
#pragma unroll
            for (int st = 0; st < 16; st++) {
                if (st <= st_max) {
                    int col = st * 16 + c16;
                    float a = (col <= row) ? accS[st][r] * 0.125f : -INFINITY;
                    accS[st][r] = a;
                    mx = fmaxf(mx, a);
                }
            }
#pragma unroll
            for (int off = 8; off; off >>= 1) mx = fmaxf(mx, __shfl_xor(mx, off));
            float sum = 0.f;
#pragma unroll
            for (int st = 0; st < 16; st++) {
                if (st < covered) {
                    float e = 0.0f;
                    if (st <= st_max) {
                        e = __expf(accS[st][r] - mx);
                        sum += e;
                    }
                    int c = st * 16 + c16;
                    __hip_bfloat16 pb = __float2bfloat16(e);
                    Pw[(c >> 5) * 512 + (((c >> 3) & 3) * 16 + quad * 4 + r) * 8 + (c & 7)] =
                        *(short*)&pb;
                }
            }
#pragma unroll
            for (int off = 8; off; off >>= 1) sum += __shfl_xor(sum, off);
            inv[r] = 1.0f / sum;
        }

        f32x4 accO[4];
#pragma unroll
        for (int nt = 0; nt < 4; nt++) accO[nt] = (f32x4){0.f, 0.f, 0.f, 0.f};
#pragma unroll
        for (int kbi = 0; kbi < 8; kbi++) {
            if (kbi < kb_count) {
                short8 ap = *(const short8*)(Pw + kbi * 512 + lane * 8);
#pragma unroll
                for (int nt = 0; nt < 4; nt++) {
                    short8 bv = *(const short8*)(vs + (kbi * 4 + nt) * 512 + lane * 8);
                    accO[nt] = __builtin_amdgcn_mfma_f32_16x16x32_bf16(ap, bv, accO[nt], 0, 0, 0);
                }
            }
        }

#pragma unroll
        for (int nt = 0; nt < 4; nt++) {
#pragma unroll
            for (int r = 0; r < 4; r++) {
                int t = qrow0 + quad * 4 + r;
                int d = nt * 16 + c16;
                o[(((size_t)b * Tn + t) * Hn + hh) * HSn + d] =
                    __float2bfloat16(accO[nt][r] * inv[r]);
            }
        }
    }
}

extern "C" void kernel_launch(void* const* d_in, const int* in_sizes, int n_in,
                              void* d_out, int out_size, void* d_ws, size_t ws_size,
                              hipStream_t stream) {
    const float* x  = (const float*)d_in[0];
    const float* Wq = (const float*)d_in[1];
    const float* Wk = (const float*)d_in[2];
    const float* Wv = (const float*)d_in[3];
    const float* Wp = (const float*)d_in[4];
    const float* bp = (const float*)d_in[5];
    const float* W1 = (const float*)d_in[6];
    const float* b1 = (const float*)d_in[7];
    const float* W2 = (const float*)d_in[8];
    const float* b2 = (const float*)d_in[9];
    const float* g1 = (const float*)d_in[10];
    const float* be1 = (const float*)d_in[11];
    const float* g2 = (const float*)d_in[12];
    const float* be2 = (const float*)d_in[13];

    const size_t M = (size_t)Bn * Tn;  // 16384
    __hip_bfloat16* ws  = (__hip_bfloat16*)d_ws;
    __hip_bfloat16* h   = ws;               // M*384 bf16 (LN1 out; reused as h2)
    __hip_bfloat16* big = h + M * Cn;       // M*1536 bf16: qkv (3*SECn; v packed) then y1
    __hip_bfloat16* o   = big + M * FFn;    // M*384 bf16 attention output [b,t,h,d]
    __hip_bfloat16* pQKV = o + M * Cn;      // 384*1152
    __hip_bfloat16* pWp  = pQKV + Cn * 1152;
    __hip_bfloat16* pW1  = pWp + Cn * Cn;
    __hip_bfloat16* pW2  = pW1 + Cn * FFn;

    float* x2 = (float*)d_out;

    pack_qkv_kernel<<<(Cn * 1152 + 255) / 256, 256, 0, stream>>>(Wq, Wk, Wv, pQKV);
    pack_b_kernel<<<(Cn * Cn + 255) / 256, 256, 0, stream>>>(Wp, pWp, Cn, Cn);
    pack_b_kernel<<<(Cn * FFn + 255) / 256, 256, 0, stream>>>(W1, pW1, Cn, FFn);
    pack_b_kernel<<<(FFn * Cn + 255) / 256, 256, 0, stream>>>(W2, pW2, FFn, Cn);

    // 1) h = LN1(x)
    ln_bf16_kernel<<<M, 128, 0, stream>>>(x, g1, be1, h);
    // 2) qkv  (GX=18 -> grid 2304); v section written fragment-packed
    gemm_mfma<Cn, 1152, 0><<<2304, 256, 0, stream>>>(h, pQKV, nullptr, nullptr, nullptr, big);
    // 3) attention: one block per (b,h), K staged in LDS
    attn_mfma_kernel<<<Bn * Hn, 256, 0, stream>>>(big, big + SECn, big + 2 * SECn, o);
    // 4) x2 = x + o@Wp + bp   (GX=6 -> 768)
    gemm_mfma<Cn, Cn, 1><<<768, 256, 0, stream>>>(o, pWp, bp, x, x2, nullptr);
    // 5) h2 = LN2(x2)
    ln_bf16_kernel<<<M, 128, 0, stream>>>(x2, g2, be2, h);
    // 6) y1 = relu(h2 @ W1 + b1)  (GX=24 -> 3072)
    gemm_mfma<Cn, FFn, 2><<<3072, 256, 0, stream>>>(h, pW1, b1, nullptr, nullptr, big);
    // 7) out = x2 + y1 @ W2 + b2  (GX=6 -> 768)
    gemm_mfma<FFn, Cn, 1><<<768, 256, 0, stream>>>(big, pW2, b2, x2, x2, nullptr);
}